// Round 5
// baseline (4266.866 us; speedup 1.0000x reference)
//
#include <hip/hip_runtime.h>
#include <math.h>

// FWI forward: 10 shots, 1000 steps, padded grid 130x160 (NBC=30).
// R5: vertical-strip sweep. Thread = 4-wide quad x 11 rows (40 quads x 12
// z-groups = 480 active of 512). 5-row rolling register window makes
// vertical neighbors register-resident: LDS traffic 40 -> 20 B/cell,
// DS instrs 202 -> ~70/thread/step, addresses fold to immediate offsets.
//   Ps: p1, halo layout stride 168 (16B-aligned center quads), 90,048 B
//   P0s: p0 rows 0..109, 70,400 B; rows 110..129 in regs of groups 10,11
//   Wv: 128 floats. Total LDS 160,960 B (< R4's proven 161,792).

#define SROW 168                 // Ps row stride (floats): col = x + 4
#define PSZ (134 * SROW)         // rows -2..131 -> 134 rows = 22,512 floats
#define P0Z (110 * 160)          // p0 rows 0..109
#define DTf 0.0008f
#define C2f 1.3333333333333333f  // 4/3
#define C3f (-0.08333333333333333f) // -1/12

#define LD4(arr, i) (*reinterpret_cast<const float4*>(&(arr)[i]))
#define LD2(arr, i) (*reinterpret_cast<const float2*>(&(arr)[i]))
#define ST4(arr, i, v) (*reinterpret_cast<float4*>(&(arr)[i]) = (v))

// ---------- setup 1: velmin reduction, Ricker wavelet, source amplitudes ----------
__global__ __launch_bounds__(1024) void fwi_setup1(const float* __restrict__ v,
                                                   float* __restrict__ ws) {
    int tid = threadIdx.x;
    float m = 3.402823466e38f;
    for (int i = tid; i < 7000; i += 1024) m = fminf(m, v[i]);
    #pragma unroll
    for (int off = 32; off > 0; off >>= 1) m = fminf(m, __shfl_down(m, off, 64));
    __shared__ float red[16];
    if ((tid & 63) == 0) red[tid >> 6] = m;
    __syncthreads();
    if (tid == 0) {
        float mm = red[0];
        for (int i = 1; i < 16; ++i) mm = fminf(mm, red[i]);
        ws[1010] = mm * 1000.0f + 3000.0f;   // denormalized velmin
    }
    // Ricker wavelet: nw=111, nc=55, f*dt*pi = 0.06283185307179587
    if (tid < 1000) {
        float w = 0.0f;
        if (tid < 111) {
            float a = (float)(55 - tid) * 0.06283185307179587f;
            float b = a * a;
            w = (1.0f - 2.0f * b) * expf(-b);
        }
        ws[tid] = w;
    }
    // src_amp[l] = ((v[1][11l]*1000+3000)*DT)^2
    if (tid >= 1000 && tid < 1010) {
        int l = tid - 1000;
        float vd = v[100 + 11 * l] * 1000.0f + 3000.0f;
        float bdt = vd * DTf;
        ws[tid] = bdt * bdt;
    }
}

// ---------- setup 2: per-cell constants, SoA: AL[c], T1[c] ----------
__global__ __launch_bounds__(256) void fwi_setup2(const float* __restrict__ v,
                                                  const float* __restrict__ ws,
                                                  float* __restrict__ AL,
                                                  float* __restrict__ T1) {
    int c = blockIdx.x * 256 + threadIdx.x;
    if (c >= 130 * 160) return;
    float velmin = ws[1010];
    int z = c / 160;
    int x = c - z * 160;
    int iz = min(max(z - 30, 0), 69);
    int ix = min(max(x - 30, 0), 99);
    float vd = v[iz * 100 + ix] * 1000.0f + 3000.0f;
    float tt = vd * DTf / 10.0f;       // v*DT/DX
    float al = tt * tt;                // alpha
    int qx = max(29 - x, x - 130);
    int qz = max(29 - z, z - 100);
    int q = (qx >= 0) ? qx : qz;
    float kdt = 0.0f;
    if (q >= 0) {
        float kap3 = 3.0f * velmin * 16.118095650958319f / 580.0f; // 3*velmin*ln(1e7)/(2*290)
        float r = (float)q * (10.0f / 290.0f);
        kdt = kap3 * (r * r) * DTf;
    }
    AL[c] = al;
    T1[c] = 2.0f - 5.0f * al - kdt;    // temp1; temp2 = t1 + 5*al - 1
}

__device__ __forceinline__ float cellq(float l2, float l1, float cc, float r1, float r2,
                                       float u1, float u2, float d1, float d2,
                                       float al, float t1, float p0) {
    float lap = C2f * ((l1 + r1) + (u1 + d1)) + C3f * ((l2 + r2) + (u2 + d2));
    float t2  = t1 + 5.0f * al - 1.0f;           // temp2 = 1 - kdt
    return t1 * cc - t2 * p0 + al * lap;
}

// ---------- main: one block per shot, 1000 steps ----------
__global__ __launch_bounds__(512) void fwi_main(const float4* __restrict__ AL4,
                                                const float4* __restrict__ T14,
                                                const float* __restrict__ ws,
                                                float* __restrict__ out) {
    __shared__ float Ps[PSZ];      // p1, haloed, stride 168 (90,048 B)
    __shared__ float P0s[P0Z];     // p0 rows 0..109 (70,400 B)
    __shared__ float Wv[128];      // Ricker wavelet (nonzero only t<111)
    const int tid = threadIdx.x;
    const int shot = blockIdx.x;

    for (int i = tid; i < PSZ; i += 512) Ps[i] = 0.0f;
    for (int i = tid; i < P0Z; i += 512) P0s[i] = 0.0f;
    if (tid < 128) Wv[tid] = (tid < 111) ? ws[tid] : 0.0f;

    const int g  = tid / 40;            // z-group 0..11 active, >=12 idle
    const int qx = tid - g * 40;        // x-quad 0..39, cells x0 = 4*qx
    const int z0 = g * 11;
    const bool act = (z0 < 130);
    const bool preg = (g >= 10);        // rows 110..129: p0 in registers
    const float amp = ws[1000 + shot];
    const int xs = 30 + 11 * shot;      // source x
    const bool isrc = (g == 2) && (qx == (xs >> 2));   // source row z=31 = g2,r9
    const int ls = xs & 3;

    const int pc0 = (z0 + 2) * SROW + 4 * qx + 4;  // Ps index of row z0 center quad
    const int p0i = z0 * 160 + 4 * qx;             // P0s index of row z0 quad
    const int cb0 = z0 * 40 + qx;                  // coefficient quad index of row z0

    float4 pn[11];                 // p_new, carried phase A -> phase B
    float4 p0r[11];                // p0 for groups 10,11 (static-indexed)
    #pragma unroll
    for (int r = 0; r < 11; ++r) p0r[r] = make_float4(0.f, 0.f, 0.f, 0.f);

    __syncthreads();

    for (int t = 0; t < 1000; ++t) {
        const float as = (t < 111) ? amp * Wv[t] : 0.0f;

        // ---- phase A: z-sweep with 5-row rolling window ----
        float4 w[5];
        if (act) {
            w[0] = LD4(Ps, pc0 - 2 * SROW);   // row z0-2
            w[1] = LD4(Ps, pc0 - 1 * SROW);   // row z0-1
            w[2] = LD4(Ps, pc0);              // row z0
            w[3] = LD4(Ps, pc0 + 1 * SROW);   // row z0+1
        }
        #pragma unroll
        for (int r = 0; r < 11; ++r) {
            if (act && (z0 + r < 130)) {
                const int pc = pc0 + r * SROW;
                w[(r + 4) % 5] = LD4(Ps, pc + 2 * SROW);    // row z+2
                float2 hl = LD2(Ps, pc - 2);                // x0-2, x0-1
                float2 hr = LD2(Ps, pc + 4);                // x0+4, x0+5
                float4 c  = w[(r + 2) % 5];
                float4 u1 = w[(r + 1) % 5];
                float4 u2 = w[(r + 0) % 5];
                float4 d1 = w[(r + 3) % 5];
                float4 d2 = w[(r + 4) % 5];
                float4 al = AL4[cb0 + r * 40];
                float4 t1 = T14[cb0 + r * 40];
                float4 p0;
                if (preg) p0 = p0r[r];
                else      p0 = LD4(P0s, p0i + r * 160);
                float4 q;
                q.x = cellq(hl.x, hl.y, c.x, c.y, c.z, u1.x, u2.x, d1.x, d2.x, al.x, t1.x, p0.x);
                q.y = cellq(hl.y, c.x,  c.y, c.z, c.w, u1.y, u2.y, d1.y, d2.y, al.y, t1.y, p0.y);
                q.z = cellq(c.x,  c.y,  c.z, c.w, hr.x, u1.z, u2.z, d1.z, d2.z, al.z, t1.z, p0.z);
                q.w = cellq(c.y,  c.z,  c.w, hr.x, hr.y, u1.w, u2.w, d1.w, d2.w, al.w, t1.w, p0.w);
                if (r == 9 && isrc) {          // source cell (z=31) post-stencil
                    q.x += (ls == 0) ? as : 0.0f;
                    q.y += (ls == 1) ? as : 0.0f;
                    q.z += (ls == 2) ? as : 0.0f;
                    q.w += (ls == 3) ? as : 0.0f;
                }
                // p0 <- old p1 center (owner-private: pre-barrier safe)
                if (preg) p0r[r] = c;
                else      ST4(P0s, p0i + r * 160, c);
                pn[r] = q;
            }
        }
        __syncthreads();               // all Ps reads complete

        // ---- phase B: commit p_new to Ps ----
        #pragma unroll
        for (int r = 0; r < 11; ++r) {
            if (act && (z0 + r < 130)) ST4(Ps, pc0 + r * SROW, pn[r]);
        }
        __syncthreads();               // Ps(p_new) visible

        // ---- phase C: receivers z=31, x=30..129 (reads only; race-free
        //      vs next phase A which also only reads Ps) ----
        if (tid < 100) out[shot * 100000 + t * 100 + tid] = Ps[33 * SROW + 34 + tid];
    }
}

extern "C" void kernel_launch(void* const* d_in, const int* in_sizes, int n_in,
                              void* d_out, int out_size, void* d_ws, size_t ws_size,
                              hipStream_t stream) {
    const float* v = (const float*)d_in[0];
    float* ws = (float*)d_ws;                        // [0..999] wavelet, [1000..1009] amps, [1010] velmin
    float* AL = (float*)((char*)d_ws + 4096);        // 20800 floats
    float* T1 = (float*)((char*)d_ws + 4096 + 83200);// 20800 floats
    float* out = (float*)d_out;

    fwi_setup1<<<1, 1024, 0, stream>>>(v, ws);
    fwi_setup2<<<82, 256, 0, stream>>>(v, ws, AL, T1);
    fwi_main<<<10, 512, 0, stream>>>((const float4*)AL, (const float4*)T1, ws, out);
}